// Round 3
// baseline (230.609 us; speedup 1.0000x reference)
//
#include <hip/hip_runtime.h>

#define D 64
#define EPSV 1e-9f

// --- CSR row offsets from sorted edge_dst via per-node lower_bound ---
__global__ void build_offsets(const int* __restrict__ edge_dst,
                              int* __restrict__ row_off,
                              int n_nodes, int n_edges) {
    int n = blockIdx.x * blockDim.x + threadIdx.x;
    if (n > n_nodes) return;
    int lo = 0, hi = n_edges;
    while (lo < hi) {
        int mid = (lo + hi) >> 1;
        if (edge_dst[mid] < n) lo = mid + 1; else hi = mid;
    }
    row_off[n] = lo;
}

// --- W2[k][d]: k<64 -> W0[d][k] ; k>=64 -> W1[d][k-64]  (concat-transposed) ---
__global__ void make_w2(const float* __restrict__ W0, const float* __restrict__ W1,
                        float* __restrict__ W2) {
    int idx = blockIdx.x * blockDim.x + threadIdx.x;
    if (idx >= 2 * D * D) return;
    int d = idx & 63, k = idx >> 6;
    W2[k * D + d] = (k < D) ? W0[d * D + k] : W1[d * D + (k - D)];
}

// --- Aggregate: one wave per node, edge-parallel slots, high occupancy.
// msg_out[n][d] = (sum_e w*feats[src][d]) / (sum_e w + eps)
__global__ __launch_bounds__(256, 8) void aggregate_kernel(
    const float* __restrict__ feats_in,
    const int*   __restrict__ row_off,
    const int*   __restrict__ edge_src,
    const float* __restrict__ edge_w,
    float* __restrict__ msg_out,
    int n_nodes)
{
    const int lane = threadIdx.x & 63;
    const int wib  = threadIdx.x >> 6;
    int node = blockIdx.x * 4 + wib;
    if (node >= n_nodes) node = n_nodes - 1;      // dup work writes identical data
    node = __builtin_amdgcn_readfirstlane(node);  // wave-uniform -> scalar loads

    const int s = row_off[node];
    const int e = row_off[node + 1];

    const int slot = lane >> 4;        // 0..3 : edge slot
    const int fo   = (lane & 15) * 4;  // 16B feature chunk

    float4 acc[4];
    #pragma unroll
    for (int j = 0; j < 4; ++j) acc[j] = make_float4(0.f, 0.f, 0.f, 0.f);
    float wsum = 0.0f;

    for (int base = s; base < e; base += 16) {
        #pragma unroll
        for (int j = 0; j < 4; ++j) {
            const int  ej = base + slot + (j << 2);
            const bool v  = ej < e;
            const float wj = v ? edge_w[ej] : 0.0f;
            const int   sj = edge_src[v ? ej : (e - 1)];
            const float4 f = *(const float4*)(feats_in + sj * D + fo);
            acc[j].x = fmaf(wj, f.x, acc[j].x);
            acc[j].y = fmaf(wj, f.y, acc[j].y);
            acc[j].z = fmaf(wj, f.z, acc[j].z);
            acc[j].w = fmaf(wj, f.w, acc[j].w);
            wsum += wj;
        }
    }

    float4 a;
    a.x = (acc[0].x + acc[1].x) + (acc[2].x + acc[3].x);
    a.y = (acc[0].y + acc[1].y) + (acc[2].y + acc[3].y);
    a.z = (acc[0].z + acc[1].z) + (acc[2].z + acc[3].z);
    a.w = (acc[0].w + acc[1].w) + (acc[2].w + acc[3].w);

    #pragma unroll
    for (int off = 16; off <= 32; off <<= 1) {
        a.x  += __shfl_xor(a.x,  off);
        a.y  += __shfl_xor(a.y,  off);
        a.z  += __shfl_xor(a.z,  off);
        a.w  += __shfl_xor(a.w,  off);
        wsum += __shfl_xor(wsum, off);
    }

    const float inv = 1.0f / (wsum + EPSV);
    if (lane < 16) {
        float4 m = make_float4(a.x * inv, a.y * inv, a.z * inv, a.w * inv);
        *(float4*)(msg_out + node * D + fo) = m;
    }
}

// --- GEMM: out[n][d] = relu( sum_k x[n][k]*W0[d][k] + msg[n][k]*W1[d][k] + b0[d]+b1[d] )
// W held in 128 VGPRs per wave (lane = d), amortized over ~25 nodes/wave.
// Per node: 16 broadcast float4 loads (x||m) + 128 FMA.
__global__ __launch_bounds__(256, 2) void gemm_kernel(
    const float* __restrict__ feats_in,
    const float* __restrict__ msgbuf,
    const float* __restrict__ W2,   // [128][64]
    const float* __restrict__ b0,
    const float* __restrict__ b1,
    float* __restrict__ out,
    int n_nodes, int total_waves)
{
    const int lane = threadIdx.x & 63;
    const int wib  = threadIdx.x >> 6;
    const int wave = __builtin_amdgcn_readfirstlane(blockIdx.x * 4 + wib);

    float wreg[2 * D];
    #pragma unroll
    for (int k = 0; k < 2 * D; ++k) wreg[k] = W2[k * D + lane];
    const float bsum = b0[lane] + b1[lane];

    for (int node = wave; node < n_nodes; node += total_waves) {
        const float4* xp = (const float4*)(feats_in + node * D);
        const float4* mp = (const float4*)(msgbuf  + node * D);
        float o = bsum;
        #pragma unroll
        for (int c = 0; c < 16; ++c) {
            const float4 xv = xp[c];
            o = fmaf(xv.x, wreg[4 * c + 0], o);
            o = fmaf(xv.y, wreg[4 * c + 1], o);
            o = fmaf(xv.z, wreg[4 * c + 2], o);
            o = fmaf(xv.w, wreg[4 * c + 3], o);
        }
        #pragma unroll
        for (int c = 0; c < 16; ++c) {
            const float4 mv = mp[c];
            o = fmaf(mv.x, wreg[D + 4 * c + 0], o);
            o = fmaf(mv.y, wreg[D + 4 * c + 1], o);
            o = fmaf(mv.z, wreg[D + 4 * c + 2], o);
            o = fmaf(mv.w, wreg[D + 4 * c + 3], o);
        }
        out[node * D + lane] = fmaxf(o, 0.0f);
    }
}

extern "C" void kernel_launch(void* const* d_in, const int* in_sizes, int n_in,
                              void* d_out, int out_size, void* d_ws, size_t ws_size,
                              hipStream_t stream) {
    const float* node_feats = (const float*)d_in[0];
    const int*   edge_src   = (const int*)  d_in[1];
    const int*   edge_dst   = (const int*)  d_in[2];
    const float* edge_w     = (const float*)d_in[3];
    const float* W0         = (const float*)d_in[4];
    const float* b0         = (const float*)d_in[5];
    const float* W1         = (const float*)d_in[6];
    const float* b1         = (const float*)d_in[7];
    float* out = (float*)d_out;

    const int n_nodes = in_sizes[0] / D;   // 50000
    const int n_edges = in_sizes[1];       // 800000

    // workspace layout
    char* ws = (char*)d_ws;
    int*   row_off   = (int*)ws;                 // (n_nodes+1) ints
    float* W2        = (float*)(ws + 204800);    // 32768 B
    float* feats_mid = (float*)(ws + 237568);    // n_nodes*D*4 = 12.8 MB
    float* msgbuf    = out;                      // d_out doubles as msg scratch

    build_offsets<<<(n_nodes + 1 + 255) / 256, 256, 0, stream>>>(edge_dst, row_off, n_nodes, n_edges);
    make_w2<<<(2 * D * D + 255) / 256, 256, 0, stream>>>(W0, W1, W2);

    const int agrid = (n_nodes + 3) / 4;
    const int ggrid = 512;                 // 2048 waves
    const int total_waves = ggrid * 4;

    // layer 0: msg -> d_out (scratch), out -> feats_mid
    aggregate_kernel<<<agrid, 256, 0, stream>>>(node_feats, row_off, edge_src, edge_w,
                                                msgbuf, n_nodes);
    gemm_kernel<<<ggrid, 256, 0, stream>>>(node_feats, msgbuf, W2, b0, b1,
                                           feats_mid, n_nodes, total_waves);
    // layer 1: msg -> d_out, then gemm reads msg[n] before writing out[n] (same wave)
    aggregate_kernel<<<agrid, 256, 0, stream>>>(feats_mid, row_off, edge_src, edge_w,
                                                msgbuf, n_nodes);
    gemm_kernel<<<ggrid, 256, 0, stream>>>(feats_mid, msgbuf, W2, b0, b1,
                                           out, n_nodes, total_waves);
}

// Round 4
// 190.066 us; speedup vs baseline: 1.2133x; 1.2133x over previous
//
#include <hip/hip_runtime.h>

#define D 64
#define EPSV 1e-9f

// --- CSR row offsets from sorted edge_dst via per-node lower_bound ---
__global__ void build_offsets(const int* __restrict__ edge_dst,
                              int* __restrict__ row_off,
                              int n_nodes, int n_edges) {
    int n = blockIdx.x * blockDim.x + threadIdx.x;
    if (n > n_nodes) return;
    int lo = 0, hi = n_edges;
    while (lo < hi) {
        int mid = (lo + hi) >> 1;
        if (edge_dst[mid] < n) lo = mid + 1; else hi = mid;
    }
    row_off[n] = lo;
}

// --- W2[k][d]: k<64 -> W0[d][k] ; k>=64 -> W1[d][k-64]  (concat-transposed) ---
__global__ void make_w2(const float* __restrict__ W0, const float* __restrict__ W1,
                        float* __restrict__ W2) {
    int idx = blockIdx.x * blockDim.x + threadIdx.x;
    if (idx >= 2 * D * D) return;
    int d = idx & 63, k = idx >> 6;
    W2[k * D + d] = (k < D) ? W0[d * D + k] : W1[d * D + (k - D)];
}

// --- Aggregate: one wave per node, edge-parallel slots, high occupancy.
// msg_out[n][d] = (sum_e w*feats[src][d]) / (sum_e w + eps)
__global__ __launch_bounds__(256, 8) void aggregate_kernel(
    const float* __restrict__ feats_in,
    const int*   __restrict__ row_off,
    const int*   __restrict__ edge_src,
    const float* __restrict__ edge_w,
    float* __restrict__ msg_out,
    int n_nodes)
{
    const int lane = threadIdx.x & 63;
    const int wib  = threadIdx.x >> 6;
    int node = blockIdx.x * 4 + wib;
    if (node >= n_nodes) node = n_nodes - 1;      // dup work writes identical data
    node = __builtin_amdgcn_readfirstlane(node);  // wave-uniform -> scalar loads

    const int s = row_off[node];
    const int e = row_off[node + 1];

    const int slot = lane >> 4;        // 0..3 : edge slot
    const int fo   = (lane & 15) * 4;  // 16B feature chunk

    float4 acc[4];
    #pragma unroll
    for (int j = 0; j < 4; ++j) acc[j] = make_float4(0.f, 0.f, 0.f, 0.f);
    float wsum = 0.0f;

    for (int base = s; base < e; base += 16) {
        #pragma unroll
        for (int j = 0; j < 4; ++j) {
            const int  ej = base + slot + (j << 2);
            const bool v  = ej < e;
            const float wj = v ? edge_w[ej] : 0.0f;
            const int   sj = edge_src[v ? ej : (e - 1)];
            const float4 f = *(const float4*)(feats_in + sj * D + fo);
            acc[j].x = fmaf(wj, f.x, acc[j].x);
            acc[j].y = fmaf(wj, f.y, acc[j].y);
            acc[j].z = fmaf(wj, f.z, acc[j].z);
            acc[j].w = fmaf(wj, f.w, acc[j].w);
            wsum += wj;
        }
    }

    float4 a;
    a.x = (acc[0].x + acc[1].x) + (acc[2].x + acc[3].x);
    a.y = (acc[0].y + acc[1].y) + (acc[2].y + acc[3].y);
    a.z = (acc[0].z + acc[1].z) + (acc[2].z + acc[3].z);
    a.w = (acc[0].w + acc[1].w) + (acc[2].w + acc[3].w);

    #pragma unroll
    for (int off = 16; off <= 32; off <<= 1) {
        a.x  += __shfl_xor(a.x,  off);
        a.y  += __shfl_xor(a.y,  off);
        a.z  += __shfl_xor(a.z,  off);
        a.w  += __shfl_xor(a.w,  off);
        wsum += __shfl_xor(wsum, off);
    }

    const float inv = 1.0f / (wsum + EPSV);
    if (lane < 16) {
        float4 m = make_float4(a.x * inv, a.y * inv, a.z * inv, a.w * inv);
        *(float4*)(msg_out + node * D + fo) = m;
    }
}

// --- GEMM: out[n][d] = relu( x[n]@W0[d,:] + msg[n]@W1[d,:] + b0[d]+b1[d] )
// Split-k across a wave PAIR: even wave holds W0' (64 VGPR) and processes x;
// odd wave holds W1' and processes msg; partials meet in LDS (256B/pair).
// No register spill by construction (wreg = 64 floats).
__global__ __launch_bounds__(256, 3) void gemm_kernel(
    const float* __restrict__ feats_in,
    const float* __restrict__ msgbuf,
    const float* __restrict__ W2,   // [128][64]
    const float* __restrict__ b0,
    const float* __restrict__ b1,
    float* __restrict__ out,
    int n_nodes, int npairs, int maxiters)
{
    __shared__ float lds[2][D];

    const int lane = threadIdx.x & 63;
    const int wib  = threadIdx.x >> 6;
    const int half = wib & 1;          // 0: x@W0, 1: msg@W1
    const int pib  = wib >> 1;         // pair-in-block 0..1
    const int pair = __builtin_amdgcn_readfirstlane(blockIdx.x * 2 + pib);

    float wreg[D];
    #pragma unroll
    for (int k = 0; k < D; ++k) wreg[k] = W2[(half * D + k) * D + lane];
    const float bsum = b0[lane] + b1[lane];

    const float* src = half ? msgbuf : feats_in;

    for (int it = 0; it < maxiters; ++it) {
        int node = pair + it * npairs;
        const bool act = node < n_nodes;
        if (!act) node = n_nodes - 1;          // clamp loads; store is guarded

        const float4* rp = (const float4*)(src + node * D);
        float o = 0.0f;
        #pragma unroll
        for (int c = 0; c < 16; ++c) {
            const float4 v = rp[c];
            o = fmaf(v.x, wreg[4 * c + 0], o);
            o = fmaf(v.y, wreg[4 * c + 1], o);
            o = fmaf(v.z, wreg[4 * c + 2], o);
            o = fmaf(v.w, wreg[4 * c + 3], o);
        }

        if (half) lds[pib][lane] = o;          // o depends on msg loads -> vmcnt drained
        __syncthreads();
        if (act && !half)
            out[node * D + lane] = fmaxf(o + lds[pib][lane] + bsum, 0.0f);
        __syncthreads();                       // protect LDS reuse next iteration
    }
}

extern "C" void kernel_launch(void* const* d_in, const int* in_sizes, int n_in,
                              void* d_out, int out_size, void* d_ws, size_t ws_size,
                              hipStream_t stream) {
    const float* node_feats = (const float*)d_in[0];
    const int*   edge_src   = (const int*)  d_in[1];
    const int*   edge_dst   = (const int*)  d_in[2];
    const float* edge_w     = (const float*)d_in[3];
    const float* W0         = (const float*)d_in[4];
    const float* b0         = (const float*)d_in[5];
    const float* W1         = (const float*)d_in[6];
    const float* b1         = (const float*)d_in[7];
    float* out = (float*)d_out;

    const int n_nodes = in_sizes[0] / D;   // 50000
    const int n_edges = in_sizes[1];       // 800000

    // workspace layout
    char* ws = (char*)d_ws;
    int*   row_off   = (int*)ws;                 // (n_nodes+1) ints
    float* W2        = (float*)(ws + 204800);    // 32768 B
    float* feats_mid = (float*)(ws + 237568);    // n_nodes*D*4 = 12.8 MB
    float* msgbuf    = out;                      // d_out doubles as msg scratch

    build_offsets<<<(n_nodes + 1 + 255) / 256, 256, 0, stream>>>(edge_dst, row_off, n_nodes, n_edges);
    make_w2<<<(2 * D * D + 255) / 256, 256, 0, stream>>>(W0, W1, W2);

    const int agrid = (n_nodes + 3) / 4;
    const int ggrid = 1024;                       // 2048 pairs
    const int npairs = ggrid * 2;
    const int maxiters = (n_nodes + npairs - 1) / npairs;

    // layer 0: msg -> d_out (scratch), out -> feats_mid
    aggregate_kernel<<<agrid, 256, 0, stream>>>(node_feats, row_off, edge_src, edge_w,
                                                msgbuf, n_nodes);
    gemm_kernel<<<ggrid, 256, 0, stream>>>(node_feats, msgbuf, W2, b0, b1,
                                           feats_mid, n_nodes, npairs, maxiters);
    // layer 1: msg -> d_out; gemm reads msg row before its owner pair writes out row
    aggregate_kernel<<<agrid, 256, 0, stream>>>(feats_mid, row_off, edge_src, edge_w,
                                                msgbuf, n_nodes);
    gemm_kernel<<<ggrid, 256, 0, stream>>>(feats_mid, msgbuf, W2, b0, b1,
                                           out, n_nodes, npairs, maxiters);
}

// Round 5
// 80.132 us; speedup vs baseline: 2.8779x; 2.3719x over previous
//
#include <hip/hip_runtime.h>

#define D 64
#define EPSV 1e-9f

typedef __attribute__((ext_vector_type(8))) short bf8_t;   // 8 x bf16
typedef __attribute__((ext_vector_type(4))) float f4_t;

__device__ inline float bf2f(short u) {
    union { unsigned int i; float f; } v;
    v.i = ((unsigned int)(unsigned short)u) << 16;
    return v.f;
}
__device__ inline unsigned short f2bf(float f) {  // round-nearest-even
    union { float f; unsigned int i; } v; v.f = f;
    unsigned int r = v.i + 0x7fff + ((v.i >> 16) & 1);
    return (unsigned short)(r >> 16);
}

// --- CSR row offsets from sorted edge_dst ---
__global__ void build_offsets(const int* __restrict__ edge_dst,
                              int* __restrict__ row_off,
                              int n_nodes, int n_edges) {
    int n = blockIdx.x * blockDim.x + threadIdx.x;
    if (n > n_nodes) return;
    int lo = 0, hi = n_edges;
    while (lo < hi) {
        int mid = (lo + hi) >> 1;
        if (edge_dst[mid] < n) lo = mid + 1; else hi = mid;
    }
    row_off[n] = lo;
}

// --- Pack W into MFMA B-fragment order, bf16.
// Wpack[((t*4+kk)*64+lane)*8+j] = W[k][col],  k=kk*32+(lane>>4)*8+j, col=t*16+(lane&15)
// where W[k][col] = k<64 ? W0[col][k] : W1[col][k-64]
__global__ void make_wpack(const float* __restrict__ W0, const float* __restrict__ W1,
                           unsigned short* __restrict__ Wpack) {
    int idx = blockIdx.x * blockDim.x + threadIdx.x;
    if (idx >= 4 * 4 * 64 * 8) return;
    int j = idx & 7, lane = (idx >> 3) & 63, kk = (idx >> 9) & 3, t = idx >> 11;
    int k = kk * 32 + (lane >> 4) * 8 + j;
    int d = t * 16 + (lane & 15);
    float v = (k < D) ? W0[d * D + k] : W1[d * D + (k - D)];
    Wpack[idx] = f2bf(v);
}

// --- node_feats f32 -> X rows (x part), bf16. X row = 128 bf16: [x | msg]
__global__ void cvt_kernel(const float* __restrict__ in,
                           unsigned short* __restrict__ X, int n_elems4) {
    int i = blockIdx.x * blockDim.x + threadIdx.x;   // one per 4 floats
    if (i >= n_elems4) return;
    const float4 v = ((const float4*)in)[i];
    int row = (i >> 4), c4 = (i & 15) * 4;           // 16 quads per row
    unsigned short* p = X + row * 128 + c4;
    p[0] = f2bf(v.x); p[1] = f2bf(v.y); p[2] = f2bf(v.z); p[3] = f2bf(v.w);
}

// --- Aggregate (bf16 feats): one wave per node.
// slot = lane>>3 (8 edge slots), fo = (lane&7)*8 (16B chunk of the 128B row).
// Writes msg (bf16) into X[node*128 + 64 ..].
__global__ __launch_bounds__(256, 8) void aggregate_kernel(
    unsigned short* __restrict__ X,       // reads x part, writes msg part
    const int*   __restrict__ row_off,
    const int*   __restrict__ edge_src,
    const float* __restrict__ edge_w,
    int n_nodes)
{
    const int lane = threadIdx.x & 63;
    const int wib  = threadIdx.x >> 6;
    int node = blockIdx.x * 4 + wib;
    if (node >= n_nodes) node = n_nodes - 1;
    node = __builtin_amdgcn_readfirstlane(node);

    const int s = row_off[node];
    const int e = row_off[node + 1];

    const int slot = lane >> 3;        // 0..7
    const int fo   = (lane & 7) * 8;   // bf16 element offset within x-part

    float acc0[8], acc1[8];
    #pragma unroll
    for (int m = 0; m < 8; ++m) { acc0[m] = 0.f; acc1[m] = 0.f; }
    float wsum = 0.0f;

    for (int base = s; base < e; base += 16) {
        {
            const int  ej = base + slot;
            const bool v  = ej < e;
            const float wj = v ? edge_w[ej] : 0.0f;
            const int   sj = edge_src[v ? ej : (e - 1)];
            const bf8_t f = *(const bf8_t*)(X + sj * 128 + fo);
            #pragma unroll
            for (int m = 0; m < 8; ++m) acc0[m] = fmaf(wj, bf2f(f[m]), acc0[m]);
            wsum += wj;
        }
        {
            const int  ej = base + 8 + slot;
            const bool v  = ej < e;
            const float wj = v ? edge_w[ej] : 0.0f;
            const int   sj = edge_src[v ? ej : (e - 1)];
            const bf8_t f = *(const bf8_t*)(X + sj * 128 + fo);
            #pragma unroll
            for (int m = 0; m < 8; ++m) acc1[m] = fmaf(wj, bf2f(f[m]), acc1[m]);
            wsum += wj;
        }
    }

    float a[8];
    #pragma unroll
    for (int m = 0; m < 8; ++m) a[m] = acc0[m] + acc1[m];

    #pragma unroll
    for (int off = 8; off <= 32; off <<= 1) {
        #pragma unroll
        for (int m = 0; m < 8; ++m) a[m] += __shfl_xor(a[m], off);
        wsum += __shfl_xor(wsum, off);
    }

    const float inv = 1.0f / (wsum + EPSV);
    if (lane < 8) {
        bf8_t mv;
        #pragma unroll
        for (int m = 0; m < 8; ++m) mv[m] = (short)f2bf(a[m] * inv);
        *(bf8_t*)(X + node * 128 + 64 + fo) = mv;
    }
}

// --- MFMA GEMM: out = relu(X2 @ Wpack + b0 + b1). One wave = 16 rows x 64 cols.
// OUT_F32: 1 -> write f32 to out; 0 -> write bf16+x-part layout into next X.
template<int OUT_F32>
__global__ __launch_bounds__(256, 4) void gemm_mfma(
    const unsigned short* __restrict__ X,      // [rows][128] bf16
    const unsigned short* __restrict__ Wpack,  // fragment-packed, 8192 bf16
    const float* __restrict__ b0,
    const float* __restrict__ b1,
    void* __restrict__ outp,
    int ntiles, int waves_total)
{
    const int lane = threadIdx.x & 63;
    const int wib  = threadIdx.x >> 6;
    const int wave = __builtin_amdgcn_readfirstlane(blockIdx.x * 4 + wib);

    // B fragments: held as MFMA operands (compiler keeps in VGPRs)
    bf8_t bf[4][4];
    #pragma unroll
    for (int t = 0; t < 4; ++t)
        #pragma unroll
        for (int kk = 0; kk < 4; ++kk)
            bf[t][kk] = *(const bf8_t*)(Wpack + ((t * 4 + kk) * 64 + lane) * 8);

    float bias[4];
    #pragma unroll
    for (int t = 0; t < 4; ++t) {
        const int col = t * 16 + (lane & 15);
        bias[t] = b0[col] + b1[col];
    }

    for (int tile = wave; tile < ntiles; tile += waves_total) {
        const int rowbase = tile * 16;
        const int arow = rowbase + (lane & 15);
        const unsigned short* ap = X + arow * 128 + (lane >> 4) * 8;

        bf8_t af[4];
        #pragma unroll
        for (int kk = 0; kk < 4; ++kk) af[kk] = *(const bf8_t*)(ap + kk * 32);

        f4_t acc[4];
        #pragma unroll
        for (int t = 0; t < 4; ++t) acc[t] = (f4_t){0.f, 0.f, 0.f, 0.f};

        #pragma unroll
        for (int t = 0; t < 4; ++t)
            #pragma unroll
            for (int kk = 0; kk < 4; ++kk)
                acc[t] = __builtin_amdgcn_mfma_f32_16x16x32_bf16(af[kk], bf[t][kk], acc[t], 0, 0, 0);

        // C layout: col = lane&15 (+16t), row = rowbase + (lane>>4)*4 + r
        #pragma unroll
        for (int t = 0; t < 4; ++t) {
            #pragma unroll
            for (int r = 0; r < 4; ++r) {
                const float v = fmaxf(acc[t][r] + bias[t], 0.0f);
                const int row = rowbase + (lane >> 4) * 4 + r;
                const int col = t * 16 + (lane & 15);
                if (OUT_F32) ((float*)outp)[row * 64 + col] = v;
                else ((unsigned short*)outp)[row * 128 + col] = f2bf(v);
            }
        }
    }
}

extern "C" void kernel_launch(void* const* d_in, const int* in_sizes, int n_in,
                              void* d_out, int out_size, void* d_ws, size_t ws_size,
                              hipStream_t stream) {
    const float* node_feats = (const float*)d_in[0];
    const int*   edge_src   = (const int*)  d_in[1];
    const int*   edge_dst   = (const int*)  d_in[2];
    const float* edge_w     = (const float*)d_in[3];
    const float* W0         = (const float*)d_in[4];
    const float* b0         = (const float*)d_in[5];
    const float* W1         = (const float*)d_in[6];
    const float* b1         = (const float*)d_in[7];

    const int n_nodes = in_sizes[0] / D;   // 50000
    const int n_edges = in_sizes[1];       // 800000

    // workspace layout
    char* ws = (char*)d_ws;
    int*            row_off = (int*)ws;                        // (n+1) ints
    unsigned short* Wpack   = (unsigned short*)(ws + 204800);  // 16384 B
    unsigned short* X0      = (unsigned short*)(ws + 237568);  // 50000*128*2 = 12.8 MB
    unsigned short* X1      = (unsigned short*)d_out;          // aliases output (12.8 MB)

    build_offsets<<<(n_nodes + 1 + 255) / 256, 256, 0, stream>>>(edge_dst, row_off, n_nodes, n_edges);
    make_wpack<<<(8192 + 255) / 256, 256, 0, stream>>>(W0, W1, Wpack);
    cvt_kernel<<<(n_nodes * 16 + 255) / 256, 256, 0, stream>>>(node_feats, X0, n_nodes * 16);

    const int agrid  = (n_nodes + 3) / 4;       // 12500
    const int ntiles = (n_nodes + 15) / 16;     // 3125
    const int ggrid  = 256;                      // 1024 waves
    const int gwaves = ggrid * 4;

    // layer 0
    aggregate_kernel<<<agrid, 256, 0, stream>>>(X0, row_off, edge_src, edge_w, n_nodes);
    gemm_mfma<0><<<ggrid, 256, 0, stream>>>(X0, Wpack, b0, b1, X1, ntiles, gwaves);
    // layer 1 (X1 aliases d_out; final gemm reads its own rows before overwriting f32)
    aggregate_kernel<<<agrid, 256, 0, stream>>>(X1, row_off, edge_src, edge_w, n_nodes);
    gemm_mfma<1><<<ggrid, 256, 0, stream>>>(X1, Wpack, b0, b1, d_out, ntiles, gwaves);
}

// Round 6
// 73.417 us; speedup vs baseline: 3.1411x; 1.0915x over previous
//
#include <hip/hip_runtime.h>

#define D 64
#define EPSV 1e-9f

typedef __attribute__((ext_vector_type(8))) short bf8_t;   // 8 x bf16
typedef __attribute__((ext_vector_type(4))) float f4_t;

__device__ inline float bf2f(short u) {
    union { unsigned int i; float f; } v;
    v.i = ((unsigned int)(unsigned short)u) << 16;
    return v.f;
}
__device__ inline unsigned short f2bf(float f) {  // round-nearest-even
    union { float f; unsigned int i; } v; v.f = f;
    unsigned int r = v.i + 0x7fff + ((v.i >> 16) & 1);
    return (unsigned short)(r >> 16);
}

// --- Fused prep: cvt (blocks [0,cvtb)), wpack (next 32), row offsets (rest) ---
__global__ void prep_kernel(const float* __restrict__ node_feats,
                            const int*   __restrict__ edge_dst,
                            const float* __restrict__ W0,
                            const float* __restrict__ W1,
                            int* __restrict__ row_off,
                            unsigned short* __restrict__ Wpack,
                            unsigned short* __restrict__ X,
                            int n_nodes, int n_edges, int cvtb)
{
    const int bid = blockIdx.x;
    const int tid = threadIdx.x;
    if (bid < cvtb) {
        // node_feats f32 -> X x-part bf16. One thread per 4 floats.
        const int i = bid * 256 + tid;
        if (i < n_nodes * 16) {
            const float4 v = ((const float4*)node_feats)[i];
            const int row = i >> 4, c4 = (i & 15) * 4;
            unsigned short* p = X + row * 128 + c4;
            p[0] = f2bf(v.x); p[1] = f2bf(v.y); p[2] = f2bf(v.z); p[3] = f2bf(v.w);
        }
    } else if (bid < cvtb + 32) {
        // W -> MFMA B-fragment order (8192 bf16):
        // Wpack[((t*4+kk)*64+lane)*8+j] = W[k][col], k=kk*32+(lane>>4)*8+j, col=t*16+(lane&15)
        const int idx = (bid - cvtb) * 256 + tid;
        const int j = idx & 7, lane = (idx >> 3) & 63, kk = (idx >> 9) & 3, t = idx >> 11;
        const int k = kk * 32 + (lane >> 4) * 8 + j;
        const int d = t * 16 + (lane & 15);
        const float v = (k < D) ? W0[d * D + k] : W1[d * D + (k - D)];
        Wpack[idx] = f2bf(v);
    } else {
        // CSR row offsets from sorted edge_dst (lower_bound)
        const int n = (bid - cvtb - 32) * 256 + tid;
        if (n <= n_nodes) {
            int lo = 0, hi = n_edges;
            while (lo < hi) {
                const int mid = (lo + hi) >> 1;
                if (edge_dst[mid] < n) lo = mid + 1; else hi = mid;
            }
            row_off[n] = lo;
        }
    }
}

// --- Aggregate: TWO nodes per wave (independent load chains), 8 edge slots,
// 16B bf16 gathers. Writes bf16 msg into X[node*128 + 64 ..].
__global__ __launch_bounds__(256, 6) void aggregate_kernel(
    unsigned short* __restrict__ X,
    const int*   __restrict__ row_off,
    const int*   __restrict__ edge_src,
    const float* __restrict__ edge_w,
    int n_nodes)
{
    const int lane = threadIdx.x & 63;
    const int wib  = threadIdx.x >> 6;
    int nA = blockIdx.x * 8 + wib * 2;
    int nB = nA + 1;
    if (nA >= n_nodes) nA = n_nodes - 1;
    if (nB >= n_nodes) nB = n_nodes - 1;
    nA = __builtin_amdgcn_readfirstlane(nA);
    nB = __builtin_amdgcn_readfirstlane(nB);

    const int sA = row_off[nA], eA = row_off[nA + 1];
    const int sB = row_off[nB], eB = row_off[nB + 1];
    const int dA = eA - sA, dB = eB - sB;
    const int dmax = dA > dB ? dA : dB;

    const int slot = lane >> 3;        // 0..7
    const int fo   = (lane & 7) * 8;   // bf16 elem offset in x-part (16B chunk)

    float aA[8], aB[8];
    #pragma unroll
    for (int m = 0; m < 8; ++m) { aA[m] = 0.f; aB[m] = 0.f; }
    float wsA = 0.f, wsB = 0.f;

    for (int base = 0; base < dmax; base += 16) {
        // phase 1: edge meta for 4 groups (guarded loads; invalid -> row 0, w=0)
        const int  ejA0 = sA + base + slot,  ejA1 = ejA0 + 8;
        const int  ejB0 = sB + base + slot,  ejB1 = ejB0 + 8;
        const bool vA0 = ejA0 < eA, vA1 = ejA1 < eA;
        const bool vB0 = ejB0 < eB, vB1 = ejB1 < eB;
        const float wA0 = vA0 ? edge_w[ejA0] : 0.f;
        const float wA1 = vA1 ? edge_w[ejA1] : 0.f;
        const float wB0 = vB0 ? edge_w[ejB0] : 0.f;
        const float wB1 = vB1 ? edge_w[ejB1] : 0.f;
        const int srcA0 = vA0 ? edge_src[ejA0] : 0;
        const int srcA1 = vA1 ? edge_src[ejA1] : 0;
        const int srcB0 = vB0 ? edge_src[ejB0] : 0;
        const int srcB1 = vB1 ? edge_src[ejB1] : 0;
        // phase 2: 4 independent gathers in flight
        const bf8_t fA0 = *(const bf8_t*)(X + srcA0 * 128 + fo);
        const bf8_t fA1 = *(const bf8_t*)(X + srcA1 * 128 + fo);
        const bf8_t fB0 = *(const bf8_t*)(X + srcB0 * 128 + fo);
        const bf8_t fB1 = *(const bf8_t*)(X + srcB1 * 128 + fo);
        // phase 3: accumulate
        #pragma unroll
        for (int m = 0; m < 8; ++m) {
            aA[m] = fmaf(wA0, bf2f(fA0[m]), fmaf(wA1, bf2f(fA1[m]), aA[m]));
            aB[m] = fmaf(wB0, bf2f(fB0[m]), fmaf(wB1, bf2f(fB1[m]), aB[m]));
        }
        wsA += wA0 + wA1;
        wsB += wB0 + wB1;
    }

    // butterfly over slot bits (lane bits 3,4,5): all lanes get totals
    #pragma unroll
    for (int off = 8; off <= 32; off <<= 1) {
        #pragma unroll
        for (int m = 0; m < 8; ++m) {
            aA[m] += __shfl_xor(aA[m], off);
            aB[m] += __shfl_xor(aB[m], off);
        }
        wsA += __shfl_xor(wsA, off);
        wsB += __shfl_xor(wsB, off);
    }

    const float invA = 1.0f / (wsA + EPSV);
    const float invB = 1.0f / (wsB + EPSV);
    if (lane < 8) {
        bf8_t mv;
        #pragma unroll
        for (int m = 0; m < 8; ++m) mv[m] = (short)f2bf(aA[m] * invA);
        *(bf8_t*)(X + nA * 128 + 64 + fo) = mv;
    } else if (lane < 16) {
        bf8_t mv;
        #pragma unroll
        for (int m = 0; m < 8; ++m) mv[m] = (short)f2bf(aB[m] * invB);
        *(bf8_t*)(X + nB * 128 + 64 + fo) = mv;
    }
}

// --- MFMA GEMM: out = relu(X @ [W0';W1'] + b0 + b1). One wave = 16 rows x 64 cols.
template<int OUT_F32>
__global__ __launch_bounds__(256, 4) void gemm_mfma(
    const unsigned short* __restrict__ X,      // [rows][128] bf16
    const unsigned short* __restrict__ Wpack,  // fragment-packed, 8192 bf16
    const float* __restrict__ b0,
    const float* __restrict__ b1,
    void* __restrict__ outp,
    int ntiles, int waves_total)
{
    const int lane = threadIdx.x & 63;
    const int wib  = threadIdx.x >> 6;
    const int wave = __builtin_amdgcn_readfirstlane(blockIdx.x * 4 + wib);

    bf8_t bf[4][4];
    #pragma unroll
    for (int t = 0; t < 4; ++t)
        #pragma unroll
        for (int kk = 0; kk < 4; ++kk)
            bf[t][kk] = *(const bf8_t*)(Wpack + ((t * 4 + kk) * 64 + lane) * 8);

    float bias[4];
    #pragma unroll
    for (int t = 0; t < 4; ++t) {
        const int col = t * 16 + (lane & 15);
        bias[t] = b0[col] + b1[col];
    }

    for (int tile = wave; tile < ntiles; tile += waves_total) {
        const int rowbase = tile * 16;
        const int arow = rowbase + (lane & 15);
        const unsigned short* ap = X + arow * 128 + (lane >> 4) * 8;

        bf8_t af[4];
        #pragma unroll
        for (int kk = 0; kk < 4; ++kk) af[kk] = *(const bf8_t*)(ap + kk * 32);

        f4_t acc[4];
        #pragma unroll
        for (int t = 0; t < 4; ++t) acc[t] = (f4_t){0.f, 0.f, 0.f, 0.f};

        #pragma unroll
        for (int t = 0; t < 4; ++t)
            #pragma unroll
            for (int kk = 0; kk < 4; ++kk)
                acc[t] = __builtin_amdgcn_mfma_f32_16x16x32_bf16(af[kk], bf[t][kk], acc[t], 0, 0, 0);

        #pragma unroll
        for (int t = 0; t < 4; ++t) {
            #pragma unroll
            for (int r = 0; r < 4; ++r) {
                const float v = fmaxf(acc[t][r] + bias[t], 0.0f);
                const int row = rowbase + (lane >> 4) * 4 + r;
                const int col = t * 16 + (lane & 15);
                if (OUT_F32) ((float*)outp)[row * 64 + col] = v;
                else ((unsigned short*)outp)[row * 128 + col] = f2bf(v);
            }
        }
    }
}

extern "C" void kernel_launch(void* const* d_in, const int* in_sizes, int n_in,
                              void* d_out, int out_size, void* d_ws, size_t ws_size,
                              hipStream_t stream) {
    const float* node_feats = (const float*)d_in[0];
    const int*   edge_src   = (const int*)  d_in[1];
    const int*   edge_dst   = (const int*)  d_in[2];
    const float* edge_w     = (const float*)d_in[3];
    const float* W0         = (const float*)d_in[4];
    const float* b0         = (const float*)d_in[5];
    const float* W1         = (const float*)d_in[6];
    const float* b1         = (const float*)d_in[7];

    const int n_nodes = in_sizes[0] / D;   // 50000
    const int n_edges = in_sizes[1];       // 800000

    // workspace layout
    char* ws = (char*)d_ws;
    int*            row_off = (int*)ws;                        // (n+1) ints
    unsigned short* Wpack   = (unsigned short*)(ws + 204800);  // 16384 B
    unsigned short* X0      = (unsigned short*)(ws + 237568);  // 12.8 MB
    unsigned short* X1      = (unsigned short*)d_out;          // aliases output

    const int cvtb = (n_nodes * 16 + 255) / 256;          // 3125
    const int offb = (n_nodes + 1 + 255) / 256;           // 196
    prep_kernel<<<cvtb + 32 + offb, 256, 0, stream>>>(node_feats, edge_dst, W0, W1,
                                                      row_off, Wpack, X0,
                                                      n_nodes, n_edges, cvtb);

    const int agrid  = (n_nodes + 7) / 8;       // 6250 (2 nodes/wave, 4 waves/block)
    const int ntiles = (n_nodes + 15) / 16;     // 3125
    const int ggrid  = 256;                     // 1024 waves
    const int gwaves = ggrid * 4;

    // layer 0
    aggregate_kernel<<<agrid, 256, 0, stream>>>(X0, row_off, edge_src, edge_w, n_nodes);
    gemm_mfma<0><<<ggrid, 256, 0, stream>>>(X0, Wpack, b0, b1, X1, ntiles, gwaves);
    // layer 1 (X1 aliases d_out; final gemm reads its own rows before overwriting f32)
    aggregate_kernel<<<agrid, 256, 0, stream>>>(X1, row_off, edge_src, edge_w, n_nodes);
    gemm_mfma<1><<<ggrid, 256, 0, stream>>>(X1, Wpack, b0, b1, d_out, ntiles, gwaves);
}